// Round 4
// baseline (895.453 us; speedup 1.0000x reference)
//
#include <hip/hip_runtime.h>

typedef _Float16 f16;
typedef _Float16 f16x8 __attribute__((ext_vector_type(8)));
typedef _Float16 f16x4 __attribute__((ext_vector_type(4)));
typedef float    f32x4 __attribute__((ext_vector_type(4)));

#define PIX          65536     // 256*256
#define PACKED_ELEMS 442368    // 18 kc * 48 nb * 64 lane * 8
#define XH_ELEMS     16777216  // 4b * 64ci * 65536

// ---------------- xcvt: x fp32 -> f16 (halves conv staging traffic) ----------------
__global__ __launch_bounds__(256) void xcvt_kernel(const float* __restrict__ x, f16* __restrict__ xh)
{
    int i = (blockIdx.x * 256 + threadIdx.x) << 3;
    f32x4 a = *reinterpret_cast<const f32x4*>(x + i);
    f32x4 b = *reinterpret_cast<const f32x4*>(x + i + 4);
    f16x8 o;
#pragma unroll
    for (int j = 0; j < 4; ++j) { o[j] = (f16)a[j]; o[j + 4] = (f16)b[j]; }
    *reinterpret_cast<f16x8*>(xh + i) = o;
}

// ---------------- prep: fold BN into weights, pack MFMA B-fragments ----------------
// packed[p], p = ((kc*48 + nb)*64 + lane)*8 + i
//   k = kc*32 + (lane>>4)*8 + i   (k = tap*64 + ci, tap = kh*3+kw)
//   n = nb*16 + (lane&15)         (n: 0-255 z, 256-511 h, 512-767 s)
__global__ void prep_kernel(
    const float* __restrict__ wz, const float* __restrict__ gz, const float* __restrict__ bz,
    const float* __restrict__ mz, const float* __restrict__ vz,
    const float* __restrict__ wh, const float* __restrict__ gh, const float* __restrict__ bh,
    const float* __restrict__ mh, const float* __restrict__ vh,
    const float* __restrict__ wq, const float* __restrict__ gq, const float* __restrict__ bq,
    const float* __restrict__ mq, const float* __restrict__ vq,
    f16* __restrict__ packed, float* __restrict__ bias)
{
    int p = blockIdx.x * 256 + threadIdx.x;
    if (p < PACKED_ELEMS) {
        int i  = p & 7;
        int l  = (p >> 3) & 63;
        int nb = (p >> 9) % 48;
        int kc = (p >> 9) / 48;
        int k  = kc * 32 + ((l >> 4) << 3) + i;
        int n  = (nb << 4) + (l & 15);
        int t  = k >> 6, ci = k & 63;
        int kh = t / 3,  kw = t % 3;
        int arr = n >> 8, co = n & 255;
        const float* w_ = arr == 0 ? wz : arr == 1 ? wh : wq;
        const float* g_ = arr == 0 ? gz : arr == 1 ? gh : gq;
        const float* v_ = arr == 0 ? vz : arr == 1 ? vh : vq;
        float inv = g_[co] / sqrtf(v_[co] + 1e-5f);
        float wv  = w_[((co * 64 + ci) * 3 + kh) * 3 + kw] * inv;
        packed[p] = (f16)wv;
    }
    if (p < 768) {
        int arr = p >> 8, co = p & 255;
        const float* g_ = arr == 0 ? gz : arr == 1 ? gh : gq;
        const float* v_ = arr == 0 ? vz : arr == 1 ? vh : vq;
        const float* b_ = arr == 0 ? bz : arr == 1 ? bh : bq;
        const float* m_ = arr == 0 ? mz : arr == 1 ? mh : mq;
        float inv = g_[co] / sqrtf(v_[co] + 1e-5f);
        bias[p] = b_[co] - m_[co] * inv;
    }
}

// ---------------- conv: implicit GEMM, phase = one 128-ch half (2 groups) of z/h/s ----------------
// grid: (nb_batches*512 M-tiles) x 3 arrays. block: 128 pixels (4 h-rows x 32 w) x 128 ch;
// 4 waves 2x2, wave = 64pix x 64ch. A-patch (6 x 34 x 64ci f16, XOR-swizzled 8-ci chunks
// keyed on wi&7) staged once per block in 26.1 KB LDS. B fragments pre-packed (L2-resident).
// Phase buffers hold 2 groups per batch: index (bloc*2 + g2)*64 + c.
__global__ __launch_bounds__(256) void conv_kernel(
    const f16* __restrict__ xh, const f16* __restrict__ Bp, const float* __restrict__ bias,
    f16* __restrict__ Zp, f16* __restrict__ Hp, f16* __restrict__ Sp, int gsel, int b0)
{
    __shared__ f16 As[6 * 34 * 64];   // 26112 B
    const int tid  = threadIdx.x;
    const int bid  = blockIdx.x;
    const int a    = bid % 3;          // 0=z 1=h 2=s
    const int mt   = bid / 3;
    const int bloc = mt >> 9;
    const int b    = b0 + bloc;
    const int rem  = mt & 511;
    const int h0   = (rem >> 3) << 2;  // 4-row group
    const int w0   = (rem & 7) << 5;   // 32-w group

    // stage xh[b][ci][h0-1..h0+4][w0-1..w0+32] -> LDS [hr][wi][ci_swz]
    for (int idx = tid; idx < 6 * 34 * 64; idx += 256) {
        int wi = idx % 34;
        int r  = idx / 34;
        int hr = r % 6;
        int ci = r / 6;
        int gh2 = h0 - 1 + hr, gw = w0 - 1 + wi;
        f16 v = (f16)0.f;
        if ((unsigned)gh2 < 256u && (unsigned)gw < 256u)
            v = xh[(((b << 6) + ci) << 16) + (gh2 << 8) + gw];
        As[((hr * 34 + wi) << 6) + ((((ci >> 3) ^ (wi & 7)) << 3)) + (ci & 7)] = v;
    }
    __syncthreads();

    const int lane = tid & 63;
    const int wave = tid >> 6;
    const int l15  = lane & 15, l4 = lane >> 4;
    const int wmo  = (wave >> 1) << 6;                    // wave M offset (0/64)
    const int nbb  = a * 16 + gsel * 8 + (wave & 1) * 4;  // wave's first 16-ch block (global)

    f32x4 acc[4][4] = {};
    const f16x8* Bv = reinterpret_cast<const f16x8*>(Bp);

    for (int kc = 0; kc < 18; ++kc) {
        const int t   = kc >> 1;
        const int dh  = t / 3, dw = t % 3;
        const int c8  = ((kc & 1) << 2) + l4;
        f16x8 bf[4], af[4];
        const f16x8* bp = Bv + ((kc * 48 + nbb) * 64 + lane);
#pragma unroll
        for (int fn = 0; fn < 4; ++fn) bf[fn] = bp[fn * 64];
#pragma unroll
        for (int fm = 0; fm < 4; ++fm) {
            int p  = wmo + fm * 16 + l15;              // pixel in [0,128)
            int wi = (p & 31) + dw;                    // 0..33
            int hr = (p >> 5) + dh;                    // 0..5
            int ai = ((hr * 34 + wi) << 6) + ((c8 ^ (wi & 7)) << 3);
            af[fm] = *reinterpret_cast<const f16x8*>(&As[ai]);
        }
#pragma unroll
        for (int fm = 0; fm < 4; ++fm)
#pragma unroll
            for (int fn = 0; fn < 4; ++fn)
                acc[fm][fn] = __builtin_amdgcn_mfma_f32_16x16x32_f16(af[fm], bf[fn], acc[fm][fn], 0, 0, 0);
    }

    // epilogue: bias (+sigmoid for z,s), f16x4 nontemporal stores (4 consecutive w)
    const bool sig = (a != 1);
    f16* arrp = (a == 0 ? Zp : a == 1 ? Hp : Sp);
#pragma unroll
    for (int fn = 0; fn < 4; ++fn) {
        const int col = ((wave & 1) << 6) + (fn << 4) + l15;   // 0..127 within phase half
        const float bs = bias[a * 256 + gsel * 128 + col];
        const int g2 = col >> 6, c = col & 63;
        f16* base = arrp + ((size_t)(((bloc << 1) + g2) * 64 + c)) * PIX;
#pragma unroll
        for (int fm = 0; fm < 4; ++fm) {
            const int p  = wmo + fm * 16 + (l4 << 2);  // + r (contiguous, same row)
            const int hl = p >> 5, wl = p & 31;
            f16x4 pk;
#pragma unroll
            for (int r = 0; r < 4; ++r) {
                float v = acc[fm][fn][r] + bs;
                if (sig) v = 1.f / (1.f + __expf(-v));
                pk[r] = (f16)v;
            }
            __builtin_nontemporal_store(pk,
                reinterpret_cast<f16x4*>(base + ((h0 + hl) << 8) + w0 + wl));
        }
    }
}

// ---------------- hscan: phase-A groups 0 (H-fwd) and 1 (H-bwd) in one pass ----------------
// thread = one w-column of one (b,c). iter i: row i (g0) + row 255-i (g1).
// First 128 iters write all 256 rows ("="), last 128 RMW ("+=") — no memset needed.
__global__ __launch_bounds__(256) void hscan_kernel(
    const f16* __restrict__ Zp, const f16* __restrict__ Hp, const f16* __restrict__ Sp,
    const float* __restrict__ h20, const float* __restrict__ h21, float* __restrict__ out, int b0)
{
    const int w = threadIdx.x;
    const int c = blockIdx.x & 63, bloc = blockIdx.x >> 6;
    const int b = b0 + bloc;
    const size_t g0 = ((size_t)(((bloc << 1) + 0) * 64 + c)) * PIX + w;
    const size_t g1 = ((size_t)(((bloc << 1) + 1) * 64 + c)) * PIX + w;
    const f16 *z0 = Zp + g0, *p0 = Hp + g0, *s0 = Sp + g0;
    const f16 *z1 = Zp + g1, *p1 = Hp + g1, *s1 = Sp + g1;
    float* o = out + ((size_t)(b * 64 + c)) * PIX + w;
    float c0 = h20[c], c1 = h21[c];
#pragma unroll 4
    for (int i = 0; i < 128; ++i) {
        const int rf = i << 8, rb = (255 - i) << 8;
        float zv = (float)__builtin_nontemporal_load(z0 + rf);
        float hv = (float)__builtin_nontemporal_load(p0 + rf);
        float sv = (float)__builtin_nontemporal_load(s0 + rf);
        c0 = fmaf(zv, hv - c0, c0);
        float zw = (float)__builtin_nontemporal_load(z1 + rb);
        float hw = (float)__builtin_nontemporal_load(p1 + rb);
        float sw = (float)__builtin_nontemporal_load(s1 + rb);
        c1 = fmaf(zw, hw - c1, c1);
        o[rf] = sv * c0;
        o[rb] = sw * c1;
    }
#pragma unroll 4
    for (int i = 128; i < 256; ++i) {
        const int rf = i << 8, rb = (255 - i) << 8;
        float zv = (float)__builtin_nontemporal_load(z0 + rf);
        float hv = (float)__builtin_nontemporal_load(p0 + rf);
        float sv = (float)__builtin_nontemporal_load(s0 + rf);
        c0 = fmaf(zv, hv - c0, c0);
        float zw = (float)__builtin_nontemporal_load(z1 + rb);
        float hw = (float)__builtin_nontemporal_load(p1 + rb);
        float sw = (float)__builtin_nontemporal_load(s1 + rb);
        c1 = fmaf(zw, hw - c1, c1);
        o[rf] += sv * c0;
        o[rb] += sw * c1;
    }
}

// ---------------- wscan: phase-B groups 2 (W-fwd), 3 (W-bwd) via affine Kogge-Stone ----------------
// wave = one row (b,c,h); lane holds 4 consecutive w. h_i = a_i*h_{i-1} + b_i composes:
// upper(A2,B2) o lower(A1,B1) = (A1*A2, A2*B1+B2). RMW final sum into d_out.
__global__ __launch_bounds__(256) void wscan_kernel(
    const f16* __restrict__ Zp, const f16* __restrict__ Hp, const f16* __restrict__ Sp,
    const float* __restrict__ h30, const float* __restrict__ h31, float* __restrict__ out, int b0)
{
    const int lane = threadIdx.x & 63;
    const int wid  = (blockIdx.x << 2) + (threadIdx.x >> 6);
    const int hrow = wid & 255, c = (wid >> 8) & 63, bloc = wid >> 14;
    const int b = b0 + bloc;
    const size_t g2 = ((size_t)(((bloc << 1) + 0) * 64 + c)) * PIX + (hrow << 8) + (lane << 2);
    const size_t g3 = ((size_t)(((bloc << 1) + 1) * 64 + c)) * PIX + (hrow << 8) + (lane << 2);
    f16x4 z2 = __builtin_nontemporal_load(reinterpret_cast<const f16x4*>(Zp + g2));
    f16x4 p2 = __builtin_nontemporal_load(reinterpret_cast<const f16x4*>(Hp + g2));
    f16x4 s2 = __builtin_nontemporal_load(reinterpret_cast<const f16x4*>(Sp + g2));
    f16x4 z3 = __builtin_nontemporal_load(reinterpret_cast<const f16x4*>(Zp + g3));
    f16x4 p3 = __builtin_nontemporal_load(reinterpret_cast<const f16x4*>(Hp + g3));
    f16x4 s3 = __builtin_nontemporal_load(reinterpret_cast<const f16x4*>(Sp + g3));

    float a2[4], b2[4], a3[4], b3[4], res[4];
#pragma unroll
    for (int j = 0; j < 4; ++j) {
        float zf = (float)z2[j], hf = (float)p2[j];
        a2[j] = 1.f - zf; b2[j] = zf * hf;
        zf = (float)z3[j]; hf = (float)p3[j];
        a3[j] = 1.f - zf; b3[j] = zf * hf;
    }
    // ---- forward (group 2) ----
    float A = a2[0], Bq = b2[0];
#pragma unroll
    for (int j = 1; j < 4; ++j) { Bq = a2[j] * Bq + b2[j]; A *= a2[j]; }
#pragma unroll
    for (int d = 1; d < 64; d <<= 1) {
        float oA = __shfl_up(A, d), oB = __shfl_up(Bq, d);
        if (lane >= d) { Bq = A * oB + Bq; A = A * oA; }
    }
    {
        float oA = __shfl_up(A, 1), oB = __shfl_up(Bq, 1);
        float xv = h30[c];
        if (lane > 0) xv = oA * xv + oB;
#pragma unroll
        for (int j = 0; j < 4; ++j) { xv = a2[j] * xv + b2[j]; res[j] = (float)s2[j] * xv; }
    }
    // ---- backward (group 3) ----
    A = a3[3]; Bq = b3[3];
#pragma unroll
    for (int j = 2; j >= 0; --j) { Bq = a3[j] * Bq + b3[j]; A *= a3[j]; }
#pragma unroll
    for (int d = 1; d < 64; d <<= 1) {
        float oA = __shfl_down(A, d), oB = __shfl_down(Bq, d);
        if (lane + d < 64) { Bq = A * oB + Bq; A = A * oA; }
    }
    {
        float oA = __shfl_down(A, 1), oB = __shfl_down(Bq, 1);
        float xv = h31[c];
        if (lane < 63) xv = oA * xv + oB;
#pragma unroll
        for (int j = 3; j >= 0; --j) { xv = a3[j] * xv + b3[j]; res[j] += (float)s3[j] * xv; }
    }
    float* op = out + ((size_t)(b * 64 + c)) * PIX + (hrow << 8) + (lane << 2);
    f32x4 prev = *(const f32x4*)op, nv;
#pragma unroll
    for (int j = 0; j < 4; ++j) nv[j] = prev[j] + res[j];
    *(f32x4*)op = nv;
}

extern "C" void kernel_launch(void* const* d_in, const int* in_sizes, int n_in,
                              void* d_out, int out_size, void* d_ws, size_t ws_size,
                              hipStream_t stream)
{
    (void)in_sizes; (void)n_in; (void)out_size;
    const float* xs  = (const float*)d_in[0];
    const float* wz  = (const float*)d_in[1];
    const float* gz  = (const float*)d_in[2];
    const float* bz  = (const float*)d_in[3];
    const float* mz  = (const float*)d_in[4];
    const float* vz  = (const float*)d_in[5];
    const float* wh  = (const float*)d_in[6];
    const float* gh  = (const float*)d_in[7];
    const float* bh  = (const float*)d_in[8];
    const float* mh  = (const float*)d_in[9];
    const float* vh  = (const float*)d_in[10];
    const float* wq  = (const float*)d_in[11];
    const float* gq  = (const float*)d_in[12];
    const float* bq  = (const float*)d_in[13];
    const float* mq  = (const float*)d_in[14];
    const float* vq  = (const float*)d_in[15];
    const float* h20 = (const float*)d_in[16];
    const float* h21 = (const float*)d_in[17];
    const float* h30 = (const float*)d_in[18];
    const float* h31 = (const float*)d_in[19];
    float* out = (float*)d_out;

    // ---- workspace layout (bytes; d_ws is >=256B aligned) ----
    char* ws = (char*)d_ws;
    f16*   Bp   = (f16*)ws;                               // 884736 B
    float* bias = (float*)(ws + 884736);                  // 3072 B
    f16*   xh   = (f16*)(ws + 884736 + 3072);             // 32 MiB
    char*  bufs = ws + 884736 + 3072 + (size_t)XH_ELEMS * 2;
    const size_t fixed = 884736 + 3072 + (size_t)XH_ELEMS * 2;

    // choose batches-per-pass nb in {4,2,1}: need fixed + nb * 3 * 16 MiB
    const size_t per_b = (size_t)3 * 2 * 64 * PIX * 2;    // 48 MiB per batch (3 arrays)
    const int nb = (ws_size >= fixed + 4 * per_b) ? 4
                 : (ws_size >= fixed + 2 * per_b) ? 2 : 1;
    const size_t arr_sz = (size_t)nb * 2 * 64 * PIX * 2;  // per-array bytes
    f16* Zp = (f16*)bufs;
    f16* Hp = (f16*)(bufs + arr_sz);
    f16* Sp = (f16*)(bufs + 2 * arr_sz);

    xcvt_kernel<<<XH_ELEMS / (256 * 8), 256, 0, stream>>>(xs, xh);
    prep_kernel<<<PACKED_ELEMS / 256, 256, 0, stream>>>(
        wz, gz, bz, mz, vz, wh, gh, bh, mh, vh, wq, gq, bq, mq, vq, Bp, bias);

    for (int b0 = 0; b0 < 4; b0 += nb) {
        // phase A: groups 0,1 -> hscan
        conv_kernel<<<nb * 512 * 3, 256, 0, stream>>>(xh, Bp, bias, Zp, Hp, Sp, 0, b0);
        hscan_kernel<<<nb * 64, 256, 0, stream>>>(Zp, Hp, Sp, h20, h21, out, b0);
        // phase B: groups 2,3 -> wscan (RMW into out)
        conv_kernel<<<nb * 512 * 3, 256, 0, stream>>>(xh, Bp, bias, Zp, Hp, Sp, 1, b0);
        wscan_kernel<<<nb * 4096, 256, 0, stream>>>(Zp, Hp, Sp, h30, h31, out, b0);
    }
}

// Round 7
// 750.743 us; speedup vs baseline: 1.1928x; 1.1928x over previous
//
#include <hip/hip_runtime.h>

typedef _Float16 f16;
typedef _Float16 f16x8 __attribute__((ext_vector_type(8)));
typedef _Float16 f16x4 __attribute__((ext_vector_type(4)));
typedef float    f32x4 __attribute__((ext_vector_type(4)));

#define PIX          65536     // 256*256
#define PACKED_ELEMS 442368    // 18 kc * 48 nb * 64 lane * 8
#define PADW         258       // padded spatial dim
#define XHS_BYTES    34080768  // 4b * 258 * 258 * 64 * 2B

// async 16B global->LDS copy (LDS dest wave-uniform base + lane*16)
__device__ __forceinline__ void gload_lds16(const f16* g, f16* l) {
    __builtin_amdgcn_global_load_lds(
        (const __attribute__((address_space(1))) void*)g,
        (__attribute__((address_space(3))) void*)l, 16, 0, 0);
}

// ---------------- xcvt: x fp32 [b][ci][h][w] -> f16 padded/transposed/pre-swizzled ----------------
// xh_s[b][hp][wp][cs], hp=h+1, wp=w+1, cs = ((ci>>3) ^ (wp&7))*8 + (ci&7).
// Linear LDS copies in conv then yield the XOR-swizzled layout its reads expect (T2, m173).
__global__ __launch_bounds__(256) void xcvt_kernel(const float* __restrict__ x, f16* __restrict__ xh_s)
{
    __shared__ f16 t[64][72];          // [wl][cs], row pad 72 (144B, 16B-aligned rows)
    const int tid = threadIdx.x;
    const int wt = blockIdx.x & 3, h = (blockIdx.x >> 2) & 255, b = blockIdx.x >> 10;
    const int ci = tid >> 2, wq = tid & 3;
    const float* src = x + (((size_t)((b << 6) + ci)) << 16) + (h << 8) + (wt << 6) + (wq << 4);
#pragma unroll
    for (int j4 = 0; j4 < 4; ++j4) {
        f32x4 v = *reinterpret_cast<const f32x4*>(src + (j4 << 2));
#pragma unroll
        for (int jj = 0; jj < 4; ++jj) {
            int wl = (wq << 4) + (j4 << 2) + jj;
            int cs = (((ci >> 3) ^ ((1 + wl) & 7)) << 3) + (ci & 7);
            t[wl][cs] = (f16)v[jj];
        }
    }
    __syncthreads();
    const int wl = tid >> 2, q = tid & 3;
    f16* dst = xh_s + (((size_t)b * PADW + (h + 1)) * PADW + (wt << 6) + 1 + wl) * 64 + (q << 4);
    *reinterpret_cast<f16x8*>(dst)     = *reinterpret_cast<const f16x8*>(&t[wl][(q << 4)]);
    *reinterpret_cast<f16x8*>(dst + 8) = *reinterpret_cast<const f16x8*>(&t[wl][(q << 4) + 8]);
}

// ---------------- prep: fold BN into weights, pack MFMA B-fragments ----------------
__global__ void prep_kernel(
    const float* __restrict__ wz, const float* __restrict__ gz, const float* __restrict__ bz,
    const float* __restrict__ mz, const float* __restrict__ vz,
    const float* __restrict__ wh, const float* __restrict__ gh, const float* __restrict__ bh,
    const float* __restrict__ mh, const float* __restrict__ vh,
    const float* __restrict__ wq, const float* __restrict__ gq, const float* __restrict__ bq,
    const float* __restrict__ mq, const float* __restrict__ vq,
    f16* __restrict__ packed, float* __restrict__ bias)
{
    int p = blockIdx.x * 256 + threadIdx.x;
    if (p < PACKED_ELEMS) {
        int i  = p & 7;
        int l  = (p >> 3) & 63;
        int nb = (p >> 9) % 48;
        int kc = (p >> 9) / 48;
        int k  = kc * 32 + ((l >> 4) << 3) + i;
        int n  = (nb << 4) + (l & 15);
        int t  = k >> 6, ci = k & 63;
        int kh = t / 3,  kw = t % 3;
        int arr = n >> 8, co = n & 255;
        const float* w_ = arr == 0 ? wz : arr == 1 ? wh : wq;
        const float* g_ = arr == 0 ? gz : arr == 1 ? gh : gq;
        const float* v_ = arr == 0 ? vz : arr == 1 ? vh : vq;
        float inv = g_[co] / sqrtf(v_[co] + 1e-5f);
        packed[p] = (f16)(w_[((co * 64 + ci) * 3 + kh) * 3 + kw] * inv);
    }
    if (p < 768) {
        int arr = p >> 8, co = p & 255;
        const float* g_ = arr == 0 ? gz : arr == 1 ? gh : gq;
        const float* v_ = arr == 0 ? vz : arr == 1 ? vh : vq;
        const float* b_ = arr == 0 ? bz : arr == 1 ? bh : bq;
        const float* m_ = arr == 0 ? mz : arr == 1 ? mh : mq;
        float inv = g_[co] / sqrtf(v_[co] + 1e-5f);
        bias[p] = b_[co] - m_[co] * inv;
    }
}

// ---------------- conv: implicit GEMM, async-LDS staging, fully-unrolled K ----------------
// Block: 128 pixels (4h x 32w) x 128 ch (one a-array, one gsel half); 4 waves 2x2.
// A-patch: 6 x (34 w x 64 ci) staged as 6 linear global_load_lds segments from xh_s
// (swizzle pre-baked in source). XCD-bijective block swizzle for L2 A-reuse.
__global__ __launch_bounds__(256) void conv_kernel(
    const f16* __restrict__ xh_s, const f16* __restrict__ Bp, const float* __restrict__ bias,
    f16* __restrict__ Zp, f16* __restrict__ Hp, f16* __restrict__ Sp,
    int gsel, int b0, int gdiv8)
{
    __shared__ f16 As[6 * 34 * 64];   // 26112 B
    const int tid  = threadIdx.x, lane = tid & 63, wave = tid >> 6;
    const int raw  = blockIdx.x;
    const int bid  = (raw & 7) * gdiv8 + (raw >> 3);   // bijective XCD swizzle
    const int a    = bid % 3;          // 0=z 1=h 2=s
    const int mt   = bid / 3;
    const int bloc = mt >> 9;
    const int b    = b0 + bloc;
    const int rem  = mt & 511;
    const int h0   = (rem >> 3) << 2;
    const int w0   = (rem & 7) << 5;

    {   // stage: hp = h0+hr, wp = w0..w0+33 -> As[hr][wi][cs], pure async copies
        const f16* seg = xh_s + (((size_t)b * PADW + h0) * PADW + w0) * 64;
#pragma unroll
        for (int hr = 0; hr < 6; ++hr) {
            const f16* gh = seg + hr * (PADW * 64);
            gload_lds16(gh + (tid << 3), &As[hr * 2176 + (wave << 9)]);
            if (tid < 16)
                gload_lds16(gh + 2048 + (tid << 3), &As[hr * 2176 + 2048]);
        }
    }
    __syncthreads();

    const int l15 = lane & 15, l4 = lane >> 4;
    const int wmo = (wave >> 1) << 6;
    const int nbb = a * 16 + gsel * 8 + (wave & 1) * 4;
    int hl_[4], wl_[4];
#pragma unroll
    for (int fm = 0; fm < 4; ++fm) { int p = wmo + fm * 16 + l15; hl_[fm] = p >> 5; wl_[fm] = p & 31; }

    f32x4 acc[4][4] = {};
    const f16x8* Bv = reinterpret_cast<const f16x8*>(Bp);

#pragma unroll
    for (int kc = 0; kc < 18; ++kc) {
        const int t  = kc >> 1;
        const int dh = t / 3, dw = t % 3;      // constants after unroll
        const int c8 = ((kc & 1) << 2) + l4;
        f16x8 bf[4], af[4];
        const f16x8* bp = Bv + (((kc * 48 + nbb) << 6) + lane);
#pragma unroll
        for (int fn = 0; fn < 4; ++fn) bf[fn] = bp[fn << 6];
#pragma unroll
        for (int fm = 0; fm < 4; ++fm) {
            const int wi = wl_[fm] + dw;
            const int ai = (((hl_[fm] + dh) * 34 + wi) << 6) + ((c8 ^ (wi & 7)) << 3);
            af[fm] = *reinterpret_cast<const f16x8*>(&As[ai]);
        }
#pragma unroll
        for (int fm = 0; fm < 4; ++fm)
#pragma unroll
            for (int fn = 0; fn < 4; ++fn)
                acc[fm][fn] = __builtin_amdgcn_mfma_f32_16x16x32_f16(af[fm], bf[fn], acc[fm][fn], 0, 0, 0);
    }

    const bool sig = (a != 1);
    f16* arrp = (a == 0 ? Zp : a == 1 ? Hp : Sp);
#pragma unroll
    for (int fn = 0; fn < 4; ++fn) {
        const int col = ((wave & 1) << 6) + (fn << 4) + l15;
        const float bs = bias[a * 256 + gsel * 128 + col];
        const int g2 = col >> 6, c = col & 63;
        f16* base = arrp + ((size_t)(((bloc << 1) + g2) * 64 + c)) * PIX;
#pragma unroll
        for (int fm = 0; fm < 4; ++fm) {
            const int p  = wmo + fm * 16 + (l4 << 2);
            const int hl = p >> 5, wl = p & 31;
            f16x4 pk;
#pragma unroll
            for (int r = 0; r < 4; ++r) {
                float v = acc[fm][fn][r] + bs;
                if (sig) v = 1.f / (1.f + __expf(-v));
                pk[r] = (f16)v;
            }
            __builtin_nontemporal_store(pk,
                reinterpret_cast<f16x4*>(base + ((h0 + hl) << 8) + w0 + wl));
        }
    }
}

// ---------------- hscan: 3-level chunked scan (8 chunks x 32 rows) ----------------
// A: per-chunk affine composites (A,B) for g0-fwd / g1-bwd.  8192 waves @ nb=4.
__global__ __launch_bounds__(256) void hscanA_kernel(
    const f16* __restrict__ Zp, const f16* __restrict__ Hp,
    float* __restrict__ sA0, float* __restrict__ sB0,
    float* __restrict__ sA1, float* __restrict__ sB1)
{
    const int w = threadIdx.x;
    const int j = blockIdx.x & 7, bcl = blockIdx.x >> 3;
    const int bloc = bcl >> 6, c = bcl & 63;
    const f16* z0 = Zp + ((size_t)((bloc * 2 + 0) * 64 + c)) * PIX + w;
    const f16* p0 = Hp + ((size_t)((bloc * 2 + 0) * 64 + c)) * PIX + w;
    const f16* z1 = Zp + ((size_t)((bloc * 2 + 1) * 64 + c)) * PIX + w;
    const f16* p1 = Hp + ((size_t)((bloc * 2 + 1) * 64 + c)) * PIX + w;
    const int r0 = j << 5;
    float A0 = 1.f, B0 = 0.f, A1 = 1.f, B1 = 0.f;
#pragma unroll 8
    for (int r = 0; r < 32; ++r) {
        const int rf = (r0 + r) << 8, rb = (r0 + 31 - r) << 8;
        float z  = (float)__builtin_nontemporal_load(z0 + rf);
        float hh = (float)__builtin_nontemporal_load(p0 + rf);
        float a0 = 1.f - z;
        A0 *= a0; B0 = fmaf(a0, B0, z * hh);
        float zb = (float)__builtin_nontemporal_load(z1 + rb);
        float hb = (float)__builtin_nontemporal_load(p1 + rb);
        float a1 = 1.f - zb;
        A1 *= a1; B1 = fmaf(a1, B1, zb * hb);
    }
    const int idx = (((bcl << 3) + j) << 8) + w;
    sA0[idx] = A0; sB0[idx] = B0; sA1[idx] = A1; sB1[idx] = B1;
}

// B: per-column prefix over the 8 chunk composites; writes chunk-entry carries
// in place into sA0/sA1 (read A,B then overwrite A -> safe, same thread).
__global__ __launch_bounds__(256) void hscanB_kernel(
    float* __restrict__ sA0, float* __restrict__ sB0,
    float* __restrict__ sA1, float* __restrict__ sB1,
    const float* __restrict__ h20, const float* __restrict__ h21)
{
    const int w = threadIdx.x, bcl = blockIdx.x, c = bcl & 63;
    float cur0 = h20[c];
#pragma unroll
    for (int j = 0; j < 8; ++j) {
        const int idx = (((bcl << 3) + j) << 8) + w;
        float A = sA0[idx], Bc = sB0[idx];
        sA0[idx] = cur0;
        cur0 = fmaf(A, cur0, Bc);
    }
    float cur1 = h21[c];
#pragma unroll
    for (int j = 7; j >= 0; --j) {
        const int idx = (((bcl << 3) + j) << 8) + w;
        float A = sA1[idx], Bc = sB1[idx];
        sA1[idx] = cur1;
        cur1 = fmaf(A, cur1, Bc);
    }
}

// C: apply. bwd chain buffered in 32 regs, then fwd chain + single "=" write of out.
__global__ __launch_bounds__(256) void hscanC_kernel(
    const f16* __restrict__ Zp, const f16* __restrict__ Hp, const f16* __restrict__ Sp,
    const float* __restrict__ st0, const float* __restrict__ st1,
    float* __restrict__ out, int b0)
{
    const int w = threadIdx.x;
    const int j = blockIdx.x & 7, bcl = blockIdx.x >> 3;
    const int bloc = bcl >> 6, c = bcl & 63, b = b0 + bloc;
    const size_t gb0 = ((size_t)((bloc * 2 + 0) * 64 + c)) * PIX + w;
    const size_t gb1 = ((size_t)((bloc * 2 + 1) * 64 + c)) * PIX + w;
    const int r0 = j << 5;
    const int idx = (((bcl << 3) + j) << 8) + w;
    float h1 = st1[idx];
    float h1b[32];
#pragma unroll
    for (int r = 31; r >= 0; --r) {
        const int row = (r0 + r) << 8;
        float z  = (float)__builtin_nontemporal_load(Zp + gb1 + row);
        float hh = (float)__builtin_nontemporal_load(Hp + gb1 + row);
        h1 = fmaf(z, hh - h1, h1);
        h1b[r] = h1;
    }
    float h0 = st0[idx];
    float* o = out + ((size_t)(b * 64 + c)) * PIX + w;
#pragma unroll
    for (int r = 0; r < 32; ++r) {
        const int row = (r0 + r) << 8;
        float z  = (float)__builtin_nontemporal_load(Zp + gb0 + row);
        float hh = (float)__builtin_nontemporal_load(Hp + gb0 + row);
        h0 = fmaf(z, hh - h0, h0);
        float s0 = (float)__builtin_nontemporal_load(Sp + gb0 + row);
        float s1 = (float)__builtin_nontemporal_load(Sp + gb1 + row);
        o[row] = s0 * h0 + s1 * h1b[r];
    }
}

// ---------------- wscan: groups 2 (W-fwd), 3 (W-bwd) via affine Kogge-Stone ----------------
__global__ __launch_bounds__(256) void wscan_kernel(
    const f16* __restrict__ Zp, const f16* __restrict__ Hp, const f16* __restrict__ Sp,
    const float* __restrict__ h30, const float* __restrict__ h31, float* __restrict__ out, int b0)
{
    const int lane = threadIdx.x & 63;
    const int wid  = (blockIdx.x << 2) + (threadIdx.x >> 6);
    const int hrow = wid & 255, c = (wid >> 8) & 63, bloc = wid >> 14;
    const int b = b0 + bloc;
    const size_t g2 = ((size_t)((bloc * 2 + 0) * 64 + c)) * PIX + (hrow << 8) + (lane << 2);
    const size_t g3 = ((size_t)((bloc * 2 + 1) * 64 + c)) * PIX + (hrow << 8) + (lane << 2);
    f16x4 z2 = __builtin_nontemporal_load(reinterpret_cast<const f16x4*>(Zp + g2));
    f16x4 p2 = __builtin_nontemporal_load(reinterpret_cast<const f16x4*>(Hp + g2));
    f16x4 s2 = __builtin_nontemporal_load(reinterpret_cast<const f16x4*>(Sp + g2));
    f16x4 z3 = __builtin_nontemporal_load(reinterpret_cast<const f16x4*>(Zp + g3));
    f16x4 p3 = __builtin_nontemporal_load(reinterpret_cast<const f16x4*>(Hp + g3));
    f16x4 s3 = __builtin_nontemporal_load(reinterpret_cast<const f16x4*>(Sp + g3));

    float a2[4], b2[4], a3[4], b3[4], res[4];
#pragma unroll
    for (int jj = 0; jj < 4; ++jj) {
        float zf = (float)z2[jj], hf = (float)p2[jj];
        a2[jj] = 1.f - zf; b2[jj] = zf * hf;
        zf = (float)z3[jj]; hf = (float)p3[jj];
        a3[jj] = 1.f - zf; b3[jj] = zf * hf;
    }
    float A = a2[0], Bq = b2[0];
#pragma unroll
    for (int jj = 1; jj < 4; ++jj) { Bq = a2[jj] * Bq + b2[jj]; A *= a2[jj]; }
#pragma unroll
    for (int d = 1; d < 64; d <<= 1) {
        float oA = __shfl_up(A, d), oB = __shfl_up(Bq, d);
        if (lane >= d) { Bq = A * oB + Bq; A = A * oA; }
    }
    {
        float oA = __shfl_up(A, 1), oB = __shfl_up(Bq, 1);
        float xv = h30[c];
        if (lane > 0) xv = oA * xv + oB;
#pragma unroll
        for (int jj = 0; jj < 4; ++jj) { xv = a2[jj] * xv + b2[jj]; res[jj] = (float)s2[jj] * xv; }
    }
    A = a3[3]; Bq = b3[3];
#pragma unroll
    for (int jj = 2; jj >= 0; --jj) { Bq = a3[jj] * Bq + b3[jj]; A *= a3[jj]; }
#pragma unroll
    for (int d = 1; d < 64; d <<= 1) {
        float oA = __shfl_down(A, d), oB = __shfl_down(Bq, d);
        if (lane + d < 64) { Bq = A * oB + Bq; A = A * oA; }
    }
    {
        float oA = __shfl_down(A, 1), oB = __shfl_down(Bq, 1);
        float xv = h31[c];
        if (lane < 63) xv = oA * xv + oB;
#pragma unroll
        for (int jj = 3; jj >= 0; --jj) { xv = a3[jj] * xv + b3[jj]; res[jj] += (float)s3[jj] * xv; }
    }
    float* op = out + ((size_t)(b * 64 + c)) * PIX + (hrow << 8) + (lane << 2);
    f32x4 prev = *(const f32x4*)op, nv;
#pragma unroll
    for (int jj = 0; jj < 4; ++jj) nv[jj] = prev[jj] + res[jj];
    *(f32x4*)op = nv;
}

extern "C" void kernel_launch(void* const* d_in, const int* in_sizes, int n_in,
                              void* d_out, int out_size, void* d_ws, size_t ws_size,
                              hipStream_t stream)
{
    (void)in_sizes; (void)n_in; (void)out_size;
    const float* xs  = (const float*)d_in[0];
    const float* wz  = (const float*)d_in[1];
    const float* gz  = (const float*)d_in[2];
    const float* bz  = (const float*)d_in[3];
    const float* mz  = (const float*)d_in[4];
    const float* vz  = (const float*)d_in[5];
    const float* wh  = (const float*)d_in[6];
    const float* gh  = (const float*)d_in[7];
    const float* bh  = (const float*)d_in[8];
    const float* mh  = (const float*)d_in[9];
    const float* vh  = (const float*)d_in[10];
    const float* wq  = (const float*)d_in[11];
    const float* gq  = (const float*)d_in[12];
    const float* bq  = (const float*)d_in[13];
    const float* mq  = (const float*)d_in[14];
    const float* vq  = (const float*)d_in[15];
    const float* h20 = (const float*)d_in[16];
    const float* h21 = (const float*)d_in[17];
    const float* h30 = (const float*)d_in[18];
    const float* h31 = (const float*)d_in[19];
    float* out = (float*)d_out;

    // ---- workspace layout ----
    char* ws = (char*)d_ws;
    f16*   Bp   = (f16*)ws;                                  // 884736 B
    float* bias = (float*)(ws + 884736);                     // 3072 B
    f16*   xh_s = (f16*)(ws + 887808);                       // 32.5 MiB padded/transposed
    const size_t fixed = 887808 + (size_t)XHS_BYTES;         // 34,968,576

    // per batch: summaries 4 x 512KiB = 2 MiB + buffers 3 x 16 MiB = 48 MiB
    const size_t per_b = 2097152 + 50331648;                 // 52,428,800
    const int nb = (ws_size >= fixed + 4 * per_b) ? 4
                 : (ws_size >= fixed + 2 * per_b) ? 2 : 1;
    float* sums = (float*)(ws + fixed);
    const size_t SUMN = (size_t)nb * 131072;                 // floats per summary array
    float* sA0 = sums;            float* sB0 = sums + SUMN;
    float* sA1 = sums + 2 * SUMN; float* sB1 = sums + 3 * SUMN;
    char*  bufs = ws + fixed + (size_t)nb * 2097152;
    const size_t arr_sz = (size_t)nb * 2 * 64 * PIX * 2;     // per-array bytes
    f16* Zp = (f16*)bufs;
    f16* Hp = (f16*)(bufs + arr_sz);
    f16* Sp = (f16*)(bufs + 2 * arr_sz);

    hipMemsetAsync(xh_s, 0, XHS_BYTES, stream);              // zero borders (pad=1)
    xcvt_kernel<<<4096, 256, 0, stream>>>(xs, xh_s);
    prep_kernel<<<PACKED_ELEMS / 256, 256, 0, stream>>>(
        wz, gz, bz, mz, vz, wh, gh, bh, mh, vh, wq, gq, bq, mq, vq, Bp, bias);

    const int cgrid = nb * 512 * 3;
    for (int b0 = 0; b0 < 4; b0 += nb) {
        // phase A: groups 0,1 -> chunked H-scan, writes out ("=")
        conv_kernel<<<cgrid, 256, 0, stream>>>(xh_s, Bp, bias, Zp, Hp, Sp, 0, b0, cgrid / 8);
        hscanA_kernel<<<nb * 64 * 8, 256, 0, stream>>>(Zp, Hp, sA0, sB0, sA1, sB1);
        hscanB_kernel<<<nb * 64, 256, 0, stream>>>(sA0, sB0, sA1, sB1, h20, h21);
        hscanC_kernel<<<nb * 64 * 8, 256, 0, stream>>>(Zp, Hp, Sp, sA0, sA1, out, b0);
        // phase B: groups 2,3 -> W-scan (RMW "+=" into out)
        conv_kernel<<<cgrid, 256, 0, stream>>>(xh_s, Bp, bias, Zp, Hp, Sp, 1, b0, cgrid / 8);
        wscan_kernel<<<nb * 4096, 256, 0, stream>>>(Zp, Hp, Sp, h30, h31, out, b0);
    }
}